// Round 9
// baseline (1093.482 us; speedup 1.0000x reference)
//
#include <hip/hip_runtime.h>

#define F_IN 500
#define HH 32
#define DD 64
#define LN_EPS 1e-6f
#define QCAP 100000     // slots per (cohort, writer-class) queue
#define SPAN 4096       // edges per wave in binq
#define CWN 1024        // countq window (nodes)
#define FWN 448         // fillq window (nodes)
#define FCAP 16384      // fillq LDS entry capacity (64 KB)

typedef float f32x4 __attribute__((ext_vector_type(4)));
typedef _Float16 f16x8 __attribute__((ext_vector_type(8)));
typedef _Float16 f16x2 __attribute__((ext_vector_type(2)));
typedef _Float16 h16;

// ---------------------------------------------------------------------------
// prep: W1T f16 [32 j][512 k] (zero-padded k>=500), W2T f16 [64 d][32 j]
// ---------------------------------------------------------------------------
__global__ __launch_bounds__(256)
void prep_k(const float* __restrict__ W1, const float* __restrict__ W2,
            h16* __restrict__ w1t, h16* __restrict__ w2t)
{
    int i = blockIdx.x * 256 + threadIdx.x;
    if (i < 32 * 512) {
        int j = i >> 9, k = i & 511;
        w1t[i] = (k < F_IN) ? (h16)W1[k * HH + j] : (h16)0.f;
    }
    int i2 = i - 32 * 512;
    if (i2 >= 0 && i2 < 64 * 32) {
        int d = i2 >> 5, j = i2 & 31;
        w2t[i2] = (h16)W2[j * DD + d];
    }
}

// ---------------------------------------------------------------------------
// Encoder via MFMA 16x16x32 f16 (round-6, verified absmax 3.9e-3).
// ---------------------------------------------------------------------------
__global__ __launch_bounds__(256)
void encoder_k(const float* __restrict__ x,
               const h16* __restrict__ w1t, const float* __restrict__ b1,
               const float* __restrict__ gamma, const float* __restrict__ beta,
               const h16* __restrict__ w2t, const float* __restrict__ b2,
               float* __restrict__ h0, int N)
{
    __shared__ h16 hbuf[4][512];

    const int t = threadIdx.x;
    const int w = t >> 6, l = t & 63;
    const int c0 = l & 15, kg = l >> 4;
    const int gr0 = (blockIdx.x * 4 + w) * 16;
    int rowA = gr0 + c0; if (rowA >= N) rowA = N - 1;
    const float* xr = x + (size_t)rowA * F_IN;

    float b1a = b1[c0], b1b = b1[c0 + 16];
    f32x4 acc0 = {b1a, b1a, b1a, b1a};
    f32x4 acc1 = {b1b, b1b, b1b, b1b};

    const h16* w1a = w1t + c0 * 512 + kg * 8;
    const h16* w1b = w1a + 16 * 512;

    #pragma unroll 3
    for (int ks = 0; ks < 15; ++ks) {
        const int k0 = ks * 32;
        f32x4 xa = *(const f32x4*)(xr + k0 + kg * 8);
        f32x4 xb = *(const f32x4*)(xr + k0 + kg * 8 + 4);
        f16x8 af;
        af[0] = (h16)xa[0]; af[1] = (h16)xa[1]; af[2] = (h16)xa[2]; af[3] = (h16)xa[3];
        af[4] = (h16)xb[0]; af[5] = (h16)xb[1]; af[6] = (h16)xb[2]; af[7] = (h16)xb[3];
        f16x8 bf0 = *(const f16x8*)(w1a + k0);
        f16x8 bf1 = *(const f16x8*)(w1b + k0);
        acc0 = __builtin_amdgcn_mfma_f32_16x16x32_f16(af, bf0, acc0, 0, 0, 0);
        acc1 = __builtin_amdgcn_mfma_f32_16x16x32_f16(af, bf1, acc1, 0, 0, 0);
    }
    {
        f16x8 af;
        #pragma unroll
        for (int e = 0; e < 8; ++e) {
            int k = 480 + kg * 8 + e;
            af[e] = (k < F_IN) ? (h16)xr[k] : (h16)0.f;
        }
        f16x8 bf0 = *(const f16x8*)(w1a + 480);
        f16x8 bf1 = *(const f16x8*)(w1b + 480);
        acc0 = __builtin_amdgcn_mfma_f32_16x16x32_f16(af, bf0, acc0, 0, 0, 0);
        acc1 = __builtin_amdgcn_mfma_f32_16x16x32_f16(af, bf1, acc1, 0, 0, 0);
    }

    float g0 = gamma[c0], g1 = gamma[c0 + 16];
    float be0 = beta[c0], be1 = beta[c0 + 16];
    h16* hb = hbuf[w];
    #pragma unroll
    for (int i = 0; i < 4; ++i) {
        float a0 = acc0[i], a1 = acc1[i];
        float s = a0 + a1;
        s += __shfl_xor(s, 1); s += __shfl_xor(s, 2);
        s += __shfl_xor(s, 4); s += __shfl_xor(s, 8);
        float mu = s * (1.0f / 32.0f);
        float d0 = a0 - mu, d1 = a1 - mu;
        float vv = d0 * d0 + d1 * d1;
        vv += __shfl_xor(vv, 1); vv += __shfl_xor(vv, 2);
        vv += __shfl_xor(vv, 4); vv += __shfl_xor(vv, 8);
        float is = rsqrtf(vv * (1.0f / 32.0f) + LN_EPS);
        float h0v = fmaxf(fmaf(d0 * is, g0, be0), 0.f);
        float h1v = fmaxf(fmaf(d1 * is, g1, be1), 0.f);
        int r = kg * 4 + i;
        hb[r * 32 + ((((c0 >> 3) ^ i) & 3) << 3) + (c0 & 7)] = (h16)h0v;
        hb[r * 32 + ((((2 + (c0 >> 3)) ^ i) & 3) << 3) + (c0 & 7)] = (h16)h1v;
    }
    asm volatile("s_waitcnt lgkmcnt(0)" ::: "memory");
    __builtin_amdgcn_sched_barrier(0);

    f16x8 ah = *(const f16x8*)(hb + c0 * 32 + (((kg ^ (c0 & 3)) & 3) << 3));

    f32x4 oc[4];
    #pragma unroll
    for (int tl = 0; tl < 4; ++tl) {
        float bb = b2[tl * 16 + c0];
        f32x4 ci = {bb, bb, bb, bb};
        f16x8 bw = *(const f16x8*)(w2t + (tl * 16 + c0) * 32 + kg * 8);
        oc[tl] = __builtin_amdgcn_mfma_f32_16x16x32_f16(ah, bw, ci, 0, 0, 0);
    }

    #pragma unroll
    for (int i = 0; i < 4; ++i) {
        float ss = oc[0][i] * oc[0][i] + oc[1][i] * oc[1][i]
                 + oc[2][i] * oc[2][i] + oc[3][i] * oc[3][i];
        ss += __shfl_xor(ss, 1); ss += __shfl_xor(ss, 2);
        ss += __shfl_xor(ss, 4); ss += __shfl_xor(ss, 8);
        float sc = 1.0f / fmaxf(sqrtf(ss), 1e-12f);
        int row = gr0 + kg * 4 + i;
        if (row < N) {
            #pragma unroll
            for (int tl = 0; tl < 4; ++tl)
                h0[(size_t)row * DD + tl * 16 + c0] = oc[tl][i] * sc;
        }
    }
}

// ---------------------------------------------------------------------------
__global__ void zero_k(int* __restrict__ p, int n)
{
    int i = blockIdx.x * blockDim.x + threadIdx.x;
    int stride = gridDim.x * blockDim.x;
    for (; i < n; i += stride) p[i] = 0;
}

// ---------------------------------------------------------------------------
// binq v2 (round-7, measured good): wave-autonomous two-pass span binner.
// ---------------------------------------------------------------------------
__global__ __launch_bounds__(256)
void binq_k(const int* __restrict__ erow, const int* __restrict__ ecol, int M,
            unsigned* __restrict__ queue, int* __restrict__ qcnt,
            int cw, unsigned magic)
{
    const int wid  = blockIdx.x * 4 + (threadIdx.x >> 6);
    const int lane = threadIdx.x & 63;
    const int nw   = gridDim.x * 4;
    const int cls  = blockIdx.x & 7;

    for (int s0 = wid * SPAN; s0 < M; s0 += nw * SPAN) {
        const int e1 = min(s0 + SPAN, M);
        int tc[8] = {0, 0, 0, 0, 0, 0, 0, 0};
        for (int i = s0 + lane; i < e1; i += 64) {
            int c = ecol[i];
            unsigned p = (unsigned)(((unsigned long long)(unsigned)c * magic) >> 32);
            #pragma unroll
            for (int pp = 0; pp < 8; ++pp) tc[pp] += (p == (unsigned)pp) ? 1 : 0;
        }
        #pragma unroll
        for (int pp = 0; pp < 8; ++pp) {
            #pragma unroll
            for (int m = 1; m < 64; m <<= 1) tc[pp] += __shfl_xor(tc[pp], m);
        }
        int val = tc[0];
        #pragma unroll
        for (int pp = 1; pp < 8; ++pp) val = (lane == pp) ? tc[pp] : val;
        int base = 0;
        if (lane < 8) base = atomicAdd(&qcnt[lane * 8 + cls], val);
        int bases[8], run[8];
        #pragma unroll
        for (int pp = 0; pp < 8; ++pp) { bases[pp] = __shfl(base, pp); run[pp] = 0; }

        for (int i0 = s0; i0 < e1; i0 += 64) {
            int i = i0 + lane;
            bool act = i < e1;
            int c = act ? ecol[i] : 0;
            int r = act ? erow[i] : 0;
            unsigned p = act ? (unsigned)(((unsigned long long)(unsigned)c * magic) >> 32)
                             : 0xFFu;
            unsigned pk = (unsigned)r | ((unsigned)(c - (int)p * cw) << 17);
            #pragma unroll
            for (int pp = 0; pp < 8; ++pp) {
                unsigned long long mm = __ballot(p == (unsigned)pp);
                if (p == (unsigned)pp) {
                    int rank = __popcll(mm & ((1ull << lane) - 1ull));
                    queue[(size_t)(pp * 8 + cls) * QCAP + bases[pp] + run[pp] + rank] = pk;
                }
                run[pp] += (int)__popcll(mm);
            }
        }
    }
}

// ---------------------------------------------------------------------------
// countq v2: LDS histogram per (cohort, 1024-node window). Queue slice is
// XCD-L2-hot; cnt writes coalesced; zero global atomics.
// ---------------------------------------------------------------------------
__global__ __launch_bounds__(256)
void countq_k(const unsigned* __restrict__ queue, const int* __restrict__ qcnt,
              int* __restrict__ cnt, int cw)
{
    __shared__ int lc[CWN];
    const int p = blockIdx.x & 7;
    const int w = blockIdx.x >> 3;
    const int c0 = w * CWN;
    const int wn = min(CWN, cw - c0);
    for (int i = threadIdx.x; i < wn; i += 256) lc[i] = 0;
    __syncthreads();
    #pragma unroll 1
    for (int sq = 0; sq < 8; ++sq) {
        int n = qcnt[p * 8 + sq];
        const unsigned* q = queue + (size_t)(p * 8 + sq) * QCAP;
        for (int i = threadIdx.x; i < n; i += 256) {
            int cl = (int)(q[i] >> 17) - c0;
            if ((unsigned)cl < (unsigned)wn) atomicAdd(&lc[cl], 1);
        }
    }
    __syncthreads();
    int* cb = cnt + p * cw + c0;
    for (int i = threadIdx.x; i < wn; i += 256) cb[i] = lc[i];
}

// ---------------------------------------------------------------------------
// Deterministic monotone scan: A) per-block reduce, B) scan block sums,
// C) per-block scan + dinv. start[] is globally ascending by node index.
// ---------------------------------------------------------------------------
__global__ __launch_bounds__(256)
void scanA_k(const int* __restrict__ cnt, int* __restrict__ bsum, int N)
{
    __shared__ int sd[256];
    int t = threadIdx.x;
    int v = blockIdx.x * 256 + t;
    sd[t] = (v < N) ? cnt[v] : 0;
    __syncthreads();
    #pragma unroll
    for (int o = 128; o > 0; o >>= 1) {
        if (t < o) sd[t] += sd[t + o];
        __syncthreads();
    }
    if (t == 0) bsum[blockIdx.x] = sd[0];
}

__global__ __launch_bounds__(512)
void scanB_k(const int* __restrict__ bsum, int* __restrict__ bbase, int NB)
{
    __shared__ int sd[512];
    int t = threadIdx.x;
    int v = (t < NB) ? bsum[t] : 0;
    sd[t] = v;
    __syncthreads();
    #pragma unroll
    for (int o = 1; o < 512; o <<= 1) {
        int tmp = (t >= o) ? sd[t - o] : 0;
        __syncthreads();
        sd[t] += tmp;
        __syncthreads();
    }
    if (t < NB) bbase[t] = sd[t] - v;   // exclusive base
}

__global__ __launch_bounds__(256)
void scanC_k(const int* __restrict__ cnt, const int* __restrict__ bbase,
             int* __restrict__ start, float* __restrict__ dinv, int N)
{
    __shared__ int sd[256];
    int t = threadIdx.x;
    int v = blockIdx.x * 256 + t;
    int c = (v < N) ? cnt[v] : 0;
    sd[t] = c;
    __syncthreads();
    #pragma unroll
    for (int o = 1; o < 256; o <<= 1) {
        int tmp = (t >= o) ? sd[t - o] : 0;
        __syncthreads();
        sd[t] += tmp;
        __syncthreads();
    }
    if (v < N) {
        start[v] = bbase[blockIdx.x] + sd[t] - c;
        dinv[v]  = (c > 0) ? rsqrtf((float)c) : 0.0f;
    }
}

// ---------------------------------------------------------------------------
// fillq v3: LDS counting sort per (cohort, 448-node window). Entries scatter
// into a 64KB LDS buffer (LDS atomics), then stream to csr_src coalesced.
// Zero global atomics on the fast path; guarded fallback if span > FCAP.
// ---------------------------------------------------------------------------
__global__ __launch_bounds__(256)
void fillq_k(const unsigned* __restrict__ queue, const int* __restrict__ qcnt,
             const int* __restrict__ start, int* __restrict__ cursor,
             int* __restrict__ csr_src, int cw, int M, int N)
{
    __shared__ int loff[FWN + 1];
    __shared__ int lcur[FWN];
    __shared__ unsigned lbuf[FCAP];

    const int p  = blockIdx.x & 7;
    const int w  = blockIdx.x >> 3;
    const int c0 = w * FWN;                    // window base, local to cohort
    const int wn = min(FWN, cw - c0);
    const int gn0 = p * cw + c0;

    for (int i = threadIdx.x; i <= wn; i += 256) {
        int g = gn0 + i;
        loff[i] = (g < N) ? start[g] : M;
    }
    for (int i = threadIdx.x; i < wn; i += 256) lcur[i] = 0;
    __syncthreads();

    const int base = loff[0];
    const int span = loff[wn] - base;

    if (span <= FCAP) {
        #pragma unroll 1
        for (int sq = 0; sq < 8; ++sq) {
            int n = qcnt[p * 8 + sq];
            const unsigned* q = queue + (size_t)(p * 8 + sq) * QCAP;
            for (int i = threadIdx.x; i < n; i += 256) {
                unsigned pk = q[i];
                int cl = (int)(pk >> 17) - c0;
                if ((unsigned)cl < (unsigned)wn) {
                    int pos = loff[cl] - base + atomicAdd(&lcur[cl], 1);
                    lbuf[pos] = pk & 0x1FFFFu;
                }
            }
        }
        __syncthreads();
        for (int i = threadIdx.x; i < span; i += 256)
            csr_src[base + i] = (int)lbuf[i];
    } else {
        // pathological-degree fallback (never taken for random graphs)
        #pragma unroll 1
        for (int sq = 0; sq < 8; ++sq) {
            int n = qcnt[p * 8 + sq];
            const unsigned* q = queue + (size_t)(p * 8 + sq) * QCAP;
            for (int i = threadIdx.x; i < n; i += 256) {
                unsigned pk = q[i];
                int cl = (int)(pk >> 17) - c0;
                if ((unsigned)cl < (unsigned)wn) {
                    int c = gn0 + cl;
                    int pos = start[c] + atomicAdd(&cursor[c], 1);
                    csr_src[pos] = (int)(pk & 0x1FFFFu);
                }
            }
        }
    }
}

// ---------------------------------------------------------------------------
// mirror[v][d-pair] = dinv[v] * h[v][2d..2d+1] as packed 2xf16
// ---------------------------------------------------------------------------
__global__ __launch_bounds__(256)
void mkmir_k(const float* __restrict__ h, const float* __restrict__ dinv,
             unsigned* __restrict__ m, int N)
{
    int i = blockIdx.x * 256 + threadIdx.x;
    if (i >= N * 32) return;
    float2 v = ((const float2*)h)[i];
    float dv = dinv[i >> 5];
    f16x2 hv;
    hv[0] = (h16)(v.x * dv);
    hv[1] = (h16)(v.y * dv);
    m[i] = __builtin_bit_cast(unsigned, hv);
}

// ---------------------------------------------------------------------------
// Propagation: 2 nodes per wave (32 lanes each, lane = u32 d-pair).
// hout[v] = dinv[v] * sum_r mirror[r]
// ---------------------------------------------------------------------------
__global__ __launch_bounds__(256)
void prop16_k(const unsigned* __restrict__ min_, float* __restrict__ hout,
              unsigned* __restrict__ mout,
              const int* __restrict__ start, const int* __restrict__ cnt,
              const int* __restrict__ csr_src, const float* __restrict__ dinv, int N)
{
    int v = blockIdx.x * 8 + (threadIdx.x >> 5);
    int l = threadIdx.x & 31;
    if (v >= N) return;
    int s = start[v];
    int e = s + cnt[v];
    float dv = dinv[v];
    float a0 = 0.0f, a1 = 0.0f;
    int i = s;
    for (; i + 3 < e; i += 4) {
        int r0 = csr_src[i],     r1 = csr_src[i + 1];
        int r2 = csr_src[i + 2], r3 = csr_src[i + 3];
        unsigned u0 = min_[(size_t)r0 * 32 + l];
        unsigned u1 = min_[(size_t)r1 * 32 + l];
        unsigned u2 = min_[(size_t)r2 * 32 + l];
        unsigned u3 = min_[(size_t)r3 * 32 + l];
        f16x2 h0v = __builtin_bit_cast(f16x2, u0);
        f16x2 h1v = __builtin_bit_cast(f16x2, u1);
        f16x2 h2v = __builtin_bit_cast(f16x2, u2);
        f16x2 h3v = __builtin_bit_cast(f16x2, u3);
        a0 += (float)h0v[0] + (float)h1v[0] + (float)h2v[0] + (float)h3v[0];
        a1 += (float)h0v[1] + (float)h1v[1] + (float)h2v[1] + (float)h3v[1];
    }
    for (; i < e; ++i) {
        int r = csr_src[i];
        f16x2 hv = __builtin_bit_cast(f16x2, min_[(size_t)r * 32 + l]);
        a0 += (float)hv[0];
        a1 += (float)hv[1];
    }
    float r0 = dv * a0, r1 = dv * a1;
    float2 st; st.x = r0; st.y = r1;
    *(float2*)(hout + (size_t)v * DD + 2 * l) = st;
    if (mout) {
        f16x2 mv;
        mv[0] = (h16)(dv * r0);
        mv[1] = (h16)(dv * r1);
        mout[(size_t)v * 32 + l] = __builtin_bit_cast(unsigned, mv);
    }
}

// ---------------------------------------------------------------------------
extern "C" void kernel_launch(void* const* d_in, const int* in_sizes, int n_in,
                              void* d_out, int out_size, void* d_ws, size_t ws_size,
                              hipStream_t stream)
{
    const float* x     = (const float*)d_in[0];
    const int*   ei    = (const int*)  d_in[1];
    const float* W1    = (const float*)d_in[2];
    const float* b1    = (const float*)d_in[3];
    const float* gamma = (const float*)d_in[4];
    const float* beta  = (const float*)d_in[5];
    const float* W2    = (const float*)d_in[6];
    const float* b2    = (const float*)d_in[7];
    float* out = (float*)d_out;

    const int N = in_sizes[0] / F_IN;       // 100000
    const int M = in_sizes[1] / 2;          // 3300000
    const int cw = (N + 7) / 8;             // 12500
    const unsigned magic = (unsigned)((0x100000000ULL + cw - 1) / cw);
    const int NB = (N + 255) / 256;         // 391 scan blocks
    const int* erow = ei;
    const int* ecol = ei + M;

    // workspace layout (ints)
    int* wsI = (int*)d_ws;
    int*   cnt     = wsI;                               // N
    int*   cursor  = wsI + N;                           // N
    int*   gctr    = wsI + 2 * N;                       // 4 (unused)
    int*   qcnt    = wsI + 2 * N + 4;                   // 64
    int*   bsum    = wsI + 2 * N + 68;                  // 512
    int*   bbase   = wsI + 2 * N + 580;                 // 512
    int*   startv  = wsI + 2 * N + 1092;                // N
    float* dinv    = (float*)(wsI + 3 * N + 1092);      // N
    h16*   w1t     = (h16*)(wsI + 4 * N + 1092);        // 8192 ints
    h16*   w2t     = (h16*)(wsI + 4 * N + 1092 + 8192); // 1024 ints
    int*   csr_src = wsI + 4 * N + 1092 + 9216;         // M
    unsigned* queue = (unsigned*)(csr_src + M);         // 64*QCAP
    unsigned* mir0 = queue;                             // overlays queue
    unsigned* mir1 = mir0 + (size_t)N * 32;

    // zero cursor + gctr + qcnt (contiguous)
    zero_k<<<512, 256, 0, stream>>>(wsI + N, N + 68);
    prep_k<<<(32 * 512 + 64 * 32 + 255) / 256, 256, 0, stream>>>(W1, W2, w1t, w2t);

    encoder_k<<<(N + 63) / 64, 256, 0, stream>>>(x, w1t, b1, gamma, beta, w2t, b2, out, N);

    binq_k<<<256, 256, 0, stream>>>(erow, ecol, M, queue, qcnt, cw, magic);

    const int NWC = (cw + CWN - 1) / CWN;   // 13
    countq_k<<<NWC * 8, 256, 0, stream>>>(queue, qcnt, cnt, cw);

    scanA_k<<<NB, 256, 0, stream>>>(cnt, bsum, N);
    scanB_k<<<1, 512, 0, stream>>>(bsum, bbase, NB);
    scanC_k<<<NB, 256, 0, stream>>>(cnt, bbase, startv, dinv, N);

    const int NWF = (cw + FWN - 1) / FWN;   // 28
    fillq_k<<<NWF * 8, 256, 0, stream>>>(queue, qcnt, startv, cursor, csr_src, cw, M, N);

    float* h0 = out;
    float* h1 = out + (size_t)N * DD;
    float* h2 = out + 2 * (size_t)N * DD;

    mkmir_k<<<(N * 32 + 255) / 256, 256, 0, stream>>>(h0, dinv, mir0, N);
    prop16_k<<<(N + 7) / 8, 256, 0, stream>>>(mir0, h1, mir1, startv, cnt, csr_src, dinv, N);
    prop16_k<<<(N + 7) / 8, 256, 0, stream>>>(mir1, h2, (unsigned*)nullptr, startv, cnt, csr_src, dinv, N);
}

// Round 10
// 555.970 us; speedup vs baseline: 1.9668x; 1.9668x over previous
//
#include <hip/hip_runtime.h>

#define F_IN 500
#define HH 32
#define DD 64
#define LN_EPS 1e-6f
#define QCAP 100000     // slots per (cohort, writer-class) queue
#define SPAN 4096       // edges per wave in binq
#define FWN 448         // fillq window (nodes)
#define FCAP 16384      // fillq LDS entry capacity (64 KB)

typedef float f32x4 __attribute__((ext_vector_type(4)));
typedef _Float16 f16x8 __attribute__((ext_vector_type(8)));
typedef _Float16 f16x2 __attribute__((ext_vector_type(2)));
typedef _Float16 h16;

// ---------------------------------------------------------------------------
// prep: W1T f16 [32 j][512 k] (zero-padded k>=500), W2T f16 [64 d][32 j]
// ---------------------------------------------------------------------------
__global__ __launch_bounds__(256)
void prep_k(const float* __restrict__ W1, const float* __restrict__ W2,
            h16* __restrict__ w1t, h16* __restrict__ w2t)
{
    int i = blockIdx.x * 256 + threadIdx.x;
    if (i < 32 * 512) {
        int j = i >> 9, k = i & 511;
        w1t[i] = (k < F_IN) ? (h16)W1[k * HH + j] : (h16)0.f;
    }
    int i2 = i - 32 * 512;
    if (i2 >= 0 && i2 < 64 * 32) {
        int d = i2 >> 5, j = i2 & 31;
        w2t[i2] = (h16)W2[j * DD + d];
    }
}

// ---------------------------------------------------------------------------
// Encoder via MFMA 16x16x32 f16 (round-6, verified absmax 3.9e-3).
// ---------------------------------------------------------------------------
__global__ __launch_bounds__(256)
void encoder_k(const float* __restrict__ x,
               const h16* __restrict__ w1t, const float* __restrict__ b1,
               const float* __restrict__ gamma, const float* __restrict__ beta,
               const h16* __restrict__ w2t, const float* __restrict__ b2,
               float* __restrict__ h0, int N)
{
    __shared__ h16 hbuf[4][512];

    const int t = threadIdx.x;
    const int w = t >> 6, l = t & 63;
    const int c0 = l & 15, kg = l >> 4;
    const int gr0 = (blockIdx.x * 4 + w) * 16;
    int rowA = gr0 + c0; if (rowA >= N) rowA = N - 1;
    const float* xr = x + (size_t)rowA * F_IN;

    float b1a = b1[c0], b1b = b1[c0 + 16];
    f32x4 acc0 = {b1a, b1a, b1a, b1a};
    f32x4 acc1 = {b1b, b1b, b1b, b1b};

    const h16* w1a = w1t + c0 * 512 + kg * 8;
    const h16* w1b = w1a + 16 * 512;

    #pragma unroll 3
    for (int ks = 0; ks < 15; ++ks) {
        const int k0 = ks * 32;
        f32x4 xa = *(const f32x4*)(xr + k0 + kg * 8);
        f32x4 xb = *(const f32x4*)(xr + k0 + kg * 8 + 4);
        f16x8 af;
        af[0] = (h16)xa[0]; af[1] = (h16)xa[1]; af[2] = (h16)xa[2]; af[3] = (h16)xa[3];
        af[4] = (h16)xb[0]; af[5] = (h16)xb[1]; af[6] = (h16)xb[2]; af[7] = (h16)xb[3];
        f16x8 bf0 = *(const f16x8*)(w1a + k0);
        f16x8 bf1 = *(const f16x8*)(w1b + k0);
        acc0 = __builtin_amdgcn_mfma_f32_16x16x32_f16(af, bf0, acc0, 0, 0, 0);
        acc1 = __builtin_amdgcn_mfma_f32_16x16x32_f16(af, bf1, acc1, 0, 0, 0);
    }
    {
        f16x8 af;
        #pragma unroll
        for (int e = 0; e < 8; ++e) {
            int k = 480 + kg * 8 + e;
            af[e] = (k < F_IN) ? (h16)xr[k] : (h16)0.f;
        }
        f16x8 bf0 = *(const f16x8*)(w1a + 480);
        f16x8 bf1 = *(const f16x8*)(w1b + 480);
        acc0 = __builtin_amdgcn_mfma_f32_16x16x32_f16(af, bf0, acc0, 0, 0, 0);
        acc1 = __builtin_amdgcn_mfma_f32_16x16x32_f16(af, bf1, acc1, 0, 0, 0);
    }

    float g0 = gamma[c0], g1 = gamma[c0 + 16];
    float be0 = beta[c0], be1 = beta[c0 + 16];
    h16* hb = hbuf[w];
    #pragma unroll
    for (int i = 0; i < 4; ++i) {
        float a0 = acc0[i], a1 = acc1[i];
        float s = a0 + a1;
        s += __shfl_xor(s, 1); s += __shfl_xor(s, 2);
        s += __shfl_xor(s, 4); s += __shfl_xor(s, 8);
        float mu = s * (1.0f / 32.0f);
        float d0 = a0 - mu, d1 = a1 - mu;
        float vv = d0 * d0 + d1 * d1;
        vv += __shfl_xor(vv, 1); vv += __shfl_xor(vv, 2);
        vv += __shfl_xor(vv, 4); vv += __shfl_xor(vv, 8);
        float is = rsqrtf(vv * (1.0f / 32.0f) + LN_EPS);
        float h0v = fmaxf(fmaf(d0 * is, g0, be0), 0.f);
        float h1v = fmaxf(fmaf(d1 * is, g1, be1), 0.f);
        int r = kg * 4 + i;
        hb[r * 32 + ((((c0 >> 3) ^ i) & 3) << 3) + (c0 & 7)] = (h16)h0v;
        hb[r * 32 + ((((2 + (c0 >> 3)) ^ i) & 3) << 3) + (c0 & 7)] = (h16)h1v;
    }
    asm volatile("s_waitcnt lgkmcnt(0)" ::: "memory");
    __builtin_amdgcn_sched_barrier(0);

    f16x8 ah = *(const f16x8*)(hb + c0 * 32 + (((kg ^ (c0 & 3)) & 3) << 3));

    f32x4 oc[4];
    #pragma unroll
    for (int tl = 0; tl < 4; ++tl) {
        float bb = b2[tl * 16 + c0];
        f32x4 ci = {bb, bb, bb, bb};
        f16x8 bw = *(const f16x8*)(w2t + (tl * 16 + c0) * 32 + kg * 8);
        oc[tl] = __builtin_amdgcn_mfma_f32_16x16x32_f16(ah, bw, ci, 0, 0, 0);
    }

    #pragma unroll
    for (int i = 0; i < 4; ++i) {
        float ss = oc[0][i] * oc[0][i] + oc[1][i] * oc[1][i]
                 + oc[2][i] * oc[2][i] + oc[3][i] * oc[3][i];
        ss += __shfl_xor(ss, 1); ss += __shfl_xor(ss, 2);
        ss += __shfl_xor(ss, 4); ss += __shfl_xor(ss, 8);
        float sc = 1.0f / fmaxf(sqrtf(ss), 1e-12f);
        int row = gr0 + kg * 4 + i;
        if (row < N) {
            #pragma unroll
            for (int tl = 0; tl < 4; ++tl)
                h0[(size_t)row * DD + tl * 16 + c0] = oc[tl][i] * sc;
        }
    }
}

// ---------------------------------------------------------------------------
__global__ void zero_k(int* __restrict__ p, int n)
{
    int i = blockIdx.x * blockDim.x + threadIdx.x;
    int stride = gridDim.x * blockDim.x;
    for (; i < n; i += stride) p[i] = 0;
}

// ---------------------------------------------------------------------------
// binq v2 (round-7, measured good): wave-autonomous two-pass span binner.
// ---------------------------------------------------------------------------
__global__ __launch_bounds__(256)
void binq_k(const int* __restrict__ erow, const int* __restrict__ ecol, int M,
            unsigned* __restrict__ queue, int* __restrict__ qcnt,
            int cw, unsigned magic)
{
    const int wid  = blockIdx.x * 4 + (threadIdx.x >> 6);
    const int lane = threadIdx.x & 63;
    const int nw   = gridDim.x * 4;
    const int cls  = blockIdx.x & 7;

    for (int s0 = wid * SPAN; s0 < M; s0 += nw * SPAN) {
        const int e1 = min(s0 + SPAN, M);
        int tc[8] = {0, 0, 0, 0, 0, 0, 0, 0};
        for (int i = s0 + lane; i < e1; i += 64) {
            int c = ecol[i];
            unsigned p = (unsigned)(((unsigned long long)(unsigned)c * magic) >> 32);
            #pragma unroll
            for (int pp = 0; pp < 8; ++pp) tc[pp] += (p == (unsigned)pp) ? 1 : 0;
        }
        #pragma unroll
        for (int pp = 0; pp < 8; ++pp) {
            #pragma unroll
            for (int m = 1; m < 64; m <<= 1) tc[pp] += __shfl_xor(tc[pp], m);
        }
        int val = tc[0];
        #pragma unroll
        for (int pp = 1; pp < 8; ++pp) val = (lane == pp) ? tc[pp] : val;
        int base = 0;
        if (lane < 8) base = atomicAdd(&qcnt[lane * 8 + cls], val);
        int bases[8], run[8];
        #pragma unroll
        for (int pp = 0; pp < 8; ++pp) { bases[pp] = __shfl(base, pp); run[pp] = 0; }

        for (int i0 = s0; i0 < e1; i0 += 64) {
            int i = i0 + lane;
            bool act = i < e1;
            int c = act ? ecol[i] : 0;
            int r = act ? erow[i] : 0;
            unsigned p = act ? (unsigned)(((unsigned long long)(unsigned)c * magic) >> 32)
                             : 0xFFu;
            unsigned pk = (unsigned)r | ((unsigned)(c - (int)p * cw) << 17);
            #pragma unroll
            for (int pp = 0; pp < 8; ++pp) {
                unsigned long long mm = __ballot(p == (unsigned)pp);
                if (p == (unsigned)pp) {
                    int rank = __popcll(mm & ((1ull << lane) - 1ull));
                    queue[(size_t)(pp * 8 + cls) * QCAP + bases[pp] + run[pp] + rank] = pk;
                }
                run[pp] += (int)__popcll(mm);
            }
        }
    }
}

// ---------------------------------------------------------------------------
// countq (round-7 form): 256 blocks per cohort, each scans 1/256 of the
// cohort's queues -> no read amplification, TLP-rich; atomics are XCD-local.
// ---------------------------------------------------------------------------
__global__ __launch_bounds__(256)
void countq_k(const unsigned* __restrict__ queue, const int* __restrict__ qcnt,
              int* __restrict__ cnt, int cw)
{
    const int p = blockIdx.x & 7;
    const int crank = blockIdx.x >> 3;
    const int cstride = (gridDim.x >> 3) * 256;
    int* cbase = cnt + p * cw;
    #pragma unroll 1
    for (int sq = 0; sq < 8; ++sq) {
        int n = qcnt[p * 8 + sq];
        const unsigned* q = queue + (size_t)(p * 8 + sq) * QCAP;
        for (int i = crank * 256 + threadIdx.x; i < n; i += cstride)
            atomicAdd(&cbase[q[i] >> 17], 1);
    }
}

// ---------------------------------------------------------------------------
// Deterministic monotone scan: A) per-block reduce, B) scan block sums,
// C) per-block scan + dinv. start[] is globally ascending by node index.
// ---------------------------------------------------------------------------
__global__ __launch_bounds__(256)
void scanA_k(const int* __restrict__ cnt, int* __restrict__ bsum, int N)
{
    __shared__ int sd[256];
    int t = threadIdx.x;
    int v = blockIdx.x * 256 + t;
    sd[t] = (v < N) ? cnt[v] : 0;
    __syncthreads();
    #pragma unroll
    for (int o = 128; o > 0; o >>= 1) {
        if (t < o) sd[t] += sd[t + o];
        __syncthreads();
    }
    if (t == 0) bsum[blockIdx.x] = sd[0];
}

__global__ __launch_bounds__(512)
void scanB_k(const int* __restrict__ bsum, int* __restrict__ bbase, int NB)
{
    __shared__ int sd[512];
    int t = threadIdx.x;
    int v = (t < NB) ? bsum[t] : 0;
    sd[t] = v;
    __syncthreads();
    #pragma unroll
    for (int o = 1; o < 512; o <<= 1) {
        int tmp = (t >= o) ? sd[t - o] : 0;
        __syncthreads();
        sd[t] += tmp;
        __syncthreads();
    }
    if (t < NB) bbase[t] = sd[t] - v;   // exclusive base
}

__global__ __launch_bounds__(256)
void scanC_k(const int* __restrict__ cnt, const int* __restrict__ bbase,
             int* __restrict__ start, float* __restrict__ dinv, int N)
{
    __shared__ int sd[256];
    int t = threadIdx.x;
    int v = blockIdx.x * 256 + t;
    int c = (v < N) ? cnt[v] : 0;
    sd[t] = c;
    __syncthreads();
    #pragma unroll
    for (int o = 1; o < 256; o <<= 1) {
        int tmp = (t >= o) ? sd[t - o] : 0;
        __syncthreads();
        sd[t] += tmp;
        __syncthreads();
    }
    if (v < N) {
        start[v] = bbase[blockIdx.x] + sd[t] - c;
        dinv[v]  = (c > 0) ? rsqrtf((float)c) : 0.0f;
    }
}

// ---------------------------------------------------------------------------
// fillq v4: LDS counting sort per (cohort, 448-node window) — round-9 traffic
// (ideal 13 MB writes) + fixed parallelism: 1024 threads (4 waves/SIMD) and
// 4-way unrolled scan (4 independent loads in flight per thread).
// ---------------------------------------------------------------------------
__global__ __launch_bounds__(1024)
void fillq_k(const unsigned* __restrict__ queue, const int* __restrict__ qcnt,
             const int* __restrict__ start, int* __restrict__ cursor,
             int* __restrict__ csr_src, int cw, int M, int N)
{
    __shared__ int loff[FWN + 1];
    __shared__ int lcur[FWN];
    __shared__ unsigned lbuf[FCAP];

    const int tid = threadIdx.x;
    const int p  = blockIdx.x & 7;
    const int w  = blockIdx.x >> 3;
    const int c0 = w * FWN;                    // window base, local to cohort
    const int wn = min(FWN, cw - c0);
    const int gn0 = p * cw + c0;

    for (int i = tid; i <= wn; i += 1024) {
        int g = gn0 + i;
        loff[i] = (g < N) ? start[g] : M;
    }
    for (int i = tid; i < wn; i += 1024) lcur[i] = 0;
    __syncthreads();

    const int base = loff[0];
    const int span = loff[wn] - base;

    if (span <= FCAP) {
        #pragma unroll 1
        for (int sq = 0; sq < 8; ++sq) {
            const int n = qcnt[p * 8 + sq];
            const unsigned* q = queue + (size_t)(p * 8 + sq) * QCAP;
            int i = tid;
            for (; i + 3 * 1024 < n; i += 4 * 1024) {
                unsigned e0 = q[i];
                unsigned e1 = q[i + 1024];
                unsigned e2 = q[i + 2048];
                unsigned e3 = q[i + 3072];
                int cl0 = (int)(e0 >> 17) - c0;
                int cl1 = (int)(e1 >> 17) - c0;
                int cl2 = (int)(e2 >> 17) - c0;
                int cl3 = (int)(e3 >> 17) - c0;
                if ((unsigned)cl0 < (unsigned)wn)
                    lbuf[loff[cl0] - base + atomicAdd(&lcur[cl0], 1)] = e0 & 0x1FFFFu;
                if ((unsigned)cl1 < (unsigned)wn)
                    lbuf[loff[cl1] - base + atomicAdd(&lcur[cl1], 1)] = e1 & 0x1FFFFu;
                if ((unsigned)cl2 < (unsigned)wn)
                    lbuf[loff[cl2] - base + atomicAdd(&lcur[cl2], 1)] = e2 & 0x1FFFFu;
                if ((unsigned)cl3 < (unsigned)wn)
                    lbuf[loff[cl3] - base + atomicAdd(&lcur[cl3], 1)] = e3 & 0x1FFFFu;
            }
            for (; i < n; i += 1024) {
                unsigned pk = q[i];
                int cl = (int)(pk >> 17) - c0;
                if ((unsigned)cl < (unsigned)wn)
                    lbuf[loff[cl] - base + atomicAdd(&lcur[cl], 1)] = pk & 0x1FFFFu;
            }
        }
        __syncthreads();
        for (int i = tid; i < span; i += 1024)
            csr_src[base + i] = (int)lbuf[i];
    } else {
        // pathological-degree fallback (never taken for random graphs)
        #pragma unroll 1
        for (int sq = 0; sq < 8; ++sq) {
            int n = qcnt[p * 8 + sq];
            const unsigned* q = queue + (size_t)(p * 8 + sq) * QCAP;
            for (int i = tid; i < n; i += 1024) {
                unsigned pk = q[i];
                int cl = (int)(pk >> 17) - c0;
                if ((unsigned)cl < (unsigned)wn) {
                    int c = gn0 + cl;
                    int pos = start[c] + atomicAdd(&cursor[c], 1);
                    csr_src[pos] = (int)(pk & 0x1FFFFu);
                }
            }
        }
    }
}

// ---------------------------------------------------------------------------
// mirror[v][d-pair] = dinv[v] * h[v][2d..2d+1] as packed 2xf16
// ---------------------------------------------------------------------------
__global__ __launch_bounds__(256)
void mkmir_k(const float* __restrict__ h, const float* __restrict__ dinv,
             unsigned* __restrict__ m, int N)
{
    int i = blockIdx.x * 256 + threadIdx.x;
    if (i >= N * 32) return;
    float2 v = ((const float2*)h)[i];
    float dv = dinv[i >> 5];
    f16x2 hv;
    hv[0] = (h16)(v.x * dv);
    hv[1] = (h16)(v.y * dv);
    m[i] = __builtin_bit_cast(unsigned, hv);
}

// ---------------------------------------------------------------------------
// Propagation: 2 nodes per wave (32 lanes each, lane = u32 d-pair).
// hout[v] = dinv[v] * sum_r mirror[r]
// ---------------------------------------------------------------------------
__global__ __launch_bounds__(256)
void prop16_k(const unsigned* __restrict__ min_, float* __restrict__ hout,
              unsigned* __restrict__ mout,
              const int* __restrict__ start, const int* __restrict__ cnt,
              const int* __restrict__ csr_src, const float* __restrict__ dinv, int N)
{
    int v = blockIdx.x * 8 + (threadIdx.x >> 5);
    int l = threadIdx.x & 31;
    if (v >= N) return;
    int s = start[v];
    int e = s + cnt[v];
    float dv = dinv[v];
    float a0 = 0.0f, a1 = 0.0f;
    int i = s;
    for (; i + 3 < e; i += 4) {
        int r0 = csr_src[i],     r1 = csr_src[i + 1];
        int r2 = csr_src[i + 2], r3 = csr_src[i + 3];
        unsigned u0 = min_[(size_t)r0 * 32 + l];
        unsigned u1 = min_[(size_t)r1 * 32 + l];
        unsigned u2 = min_[(size_t)r2 * 32 + l];
        unsigned u3 = min_[(size_t)r3 * 32 + l];
        f16x2 h0v = __builtin_bit_cast(f16x2, u0);
        f16x2 h1v = __builtin_bit_cast(f16x2, u1);
        f16x2 h2v = __builtin_bit_cast(f16x2, u2);
        f16x2 h3v = __builtin_bit_cast(f16x2, u3);
        a0 += (float)h0v[0] + (float)h1v[0] + (float)h2v[0] + (float)h3v[0];
        a1 += (float)h0v[1] + (float)h1v[1] + (float)h2v[1] + (float)h3v[1];
    }
    for (; i < e; ++i) {
        int r = csr_src[i];
        f16x2 hv = __builtin_bit_cast(f16x2, min_[(size_t)r * 32 + l]);
        a0 += (float)hv[0];
        a1 += (float)hv[1];
    }
    float r0 = dv * a0, r1 = dv * a1;
    float2 st; st.x = r0; st.y = r1;
    *(float2*)(hout + (size_t)v * DD + 2 * l) = st;
    if (mout) {
        f16x2 mv;
        mv[0] = (h16)(dv * r0);
        mv[1] = (h16)(dv * r1);
        mout[(size_t)v * 32 + l] = __builtin_bit_cast(unsigned, mv);
    }
}

// ---------------------------------------------------------------------------
extern "C" void kernel_launch(void* const* d_in, const int* in_sizes, int n_in,
                              void* d_out, int out_size, void* d_ws, size_t ws_size,
                              hipStream_t stream)
{
    const float* x     = (const float*)d_in[0];
    const int*   ei    = (const int*)  d_in[1];
    const float* W1    = (const float*)d_in[2];
    const float* b1    = (const float*)d_in[3];
    const float* gamma = (const float*)d_in[4];
    const float* beta  = (const float*)d_in[5];
    const float* W2    = (const float*)d_in[6];
    const float* b2    = (const float*)d_in[7];
    float* out = (float*)d_out;

    const int N = in_sizes[0] / F_IN;       // 100000
    const int M = in_sizes[1] / 2;          // 3300000
    const int cw = (N + 7) / 8;             // 12500
    const unsigned magic = (unsigned)((0x100000000ULL + cw - 1) / cw);
    const int NB = (N + 255) / 256;         // 391 scan blocks
    const int* erow = ei;
    const int* ecol = ei + M;

    // workspace layout (ints)
    int* wsI = (int*)d_ws;
    int*   cnt     = wsI;                               // N
    int*   cursor  = wsI + N;                           // N
    int*   qcnt    = wsI + 2 * N + 4;                   // 64
    int*   bsum    = wsI + 2 * N + 68;                  // 512
    int*   bbase   = wsI + 2 * N + 580;                 // 512
    int*   startv  = wsI + 2 * N + 1092;                // N
    float* dinv    = (float*)(wsI + 3 * N + 1092);      // N
    h16*   w1t     = (h16*)(wsI + 4 * N + 1092);        // 8192 ints
    h16*   w2t     = (h16*)(wsI + 4 * N + 1092 + 8192); // 1024 ints
    int*   csr_src = wsI + 4 * N + 1092 + 9216;         // M
    unsigned* queue = (unsigned*)(csr_src + M);         // 64*QCAP
    unsigned* mir0 = queue;                             // overlays queue
    unsigned* mir1 = mir0 + (size_t)N * 32;

    // zero cnt + cursor + qcnt (contiguous head region)
    zero_k<<<512, 256, 0, stream>>>(wsI, 2 * N + 68);
    prep_k<<<(32 * 512 + 64 * 32 + 255) / 256, 256, 0, stream>>>(W1, W2, w1t, w2t);

    encoder_k<<<(N + 63) / 64, 256, 0, stream>>>(x, w1t, b1, gamma, beta, w2t, b2, out, N);

    binq_k<<<256, 256, 0, stream>>>(erow, ecol, M, queue, qcnt, cw, magic);

    countq_k<<<2048, 256, 0, stream>>>(queue, qcnt, cnt, cw);

    scanA_k<<<NB, 256, 0, stream>>>(cnt, bsum, N);
    scanB_k<<<1, 512, 0, stream>>>(bsum, bbase, NB);
    scanC_k<<<NB, 256, 0, stream>>>(cnt, bbase, startv, dinv, N);

    const int NWF = (cw + FWN - 1) / FWN;   // 28
    fillq_k<<<NWF * 8, 1024, 0, stream>>>(queue, qcnt, startv, cursor, csr_src, cw, M, N);

    float* h0 = out;
    float* h1 = out + (size_t)N * DD;
    float* h2 = out + 2 * (size_t)N * DD;

    mkmir_k<<<(N * 32 + 255) / 256, 256, 0, stream>>>(h0, dinv, mir0, N);
    prop16_k<<<(N + 7) / 8, 256, 0, stream>>>(mir0, h1, mir1, startv, cnt, csr_src, dinv, N);
    prop16_k<<<(N + 7) / 8, 256, 0, stream>>>(mir1, h2, (unsigned*)nullptr, startv, cnt, csr_src, dinv, N);
}

// Round 11
// 466.732 us; speedup vs baseline: 2.3428x; 1.1912x over previous
//
#include <hip/hip_runtime.h>

#define F_IN 500
#define HH 32
#define DD 64
#define LN_EPS 1e-6f
#define QCAP 100000     // slots per (cohort, writer-class) queue
#define SPAN 4096       // edges per wave in binq
#define FWN 448         // fillq window (nodes)
#define FCAP 16384      // fillq LDS entry capacity (64 KB)

typedef float f32x4 __attribute__((ext_vector_type(4)));
typedef _Float16 f16x8 __attribute__((ext_vector_type(8)));
typedef _Float16 f16x2 __attribute__((ext_vector_type(2)));
typedef _Float16 h16;

// ---------------------------------------------------------------------------
// prep: W1T f16 [32 j][512 k] (zero-padded k>=500), W2T f16 [64 d][32 j]
// ---------------------------------------------------------------------------
__global__ __launch_bounds__(256)
void prep_k(const float* __restrict__ W1, const float* __restrict__ W2,
            h16* __restrict__ w1t, h16* __restrict__ w2t)
{
    int i = blockIdx.x * 256 + threadIdx.x;
    if (i < 32 * 512) {
        int j = i >> 9, k = i & 511;
        w1t[i] = (k < F_IN) ? (h16)W1[k * HH + j] : (h16)0.f;
    }
    int i2 = i - 32 * 512;
    if (i2 >= 0 && i2 < 64 * 32) {
        int d = i2 >> 5, j = i2 & 31;
        w2t[i2] = (h16)W2[j * DD + d];
    }
}

// ---------------------------------------------------------------------------
// Encoder via MFMA 16x16x32 f16 (round-6, verified absmax 3.9e-3).
// ---------------------------------------------------------------------------
__global__ __launch_bounds__(256)
void encoder_k(const float* __restrict__ x,
               const h16* __restrict__ w1t, const float* __restrict__ b1,
               const float* __restrict__ gamma, const float* __restrict__ beta,
               const h16* __restrict__ w2t, const float* __restrict__ b2,
               float* __restrict__ h0, int N)
{
    __shared__ h16 hbuf[4][512];

    const int t = threadIdx.x;
    const int w = t >> 6, l = t & 63;
    const int c0 = l & 15, kg = l >> 4;
    const int gr0 = (blockIdx.x * 4 + w) * 16;
    int rowA = gr0 + c0; if (rowA >= N) rowA = N - 1;
    const float* xr = x + (size_t)rowA * F_IN;

    float b1a = b1[c0], b1b = b1[c0 + 16];
    f32x4 acc0 = {b1a, b1a, b1a, b1a};
    f32x4 acc1 = {b1b, b1b, b1b, b1b};

    const h16* w1a = w1t + c0 * 512 + kg * 8;
    const h16* w1b = w1a + 16 * 512;

    #pragma unroll 3
    for (int ks = 0; ks < 15; ++ks) {
        const int k0 = ks * 32;
        f32x4 xa = *(const f32x4*)(xr + k0 + kg * 8);
        f32x4 xb = *(const f32x4*)(xr + k0 + kg * 8 + 4);
        f16x8 af;
        af[0] = (h16)xa[0]; af[1] = (h16)xa[1]; af[2] = (h16)xa[2]; af[3] = (h16)xa[3];
        af[4] = (h16)xb[0]; af[5] = (h16)xb[1]; af[6] = (h16)xb[2]; af[7] = (h16)xb[3];
        f16x8 bf0 = *(const f16x8*)(w1a + k0);
        f16x8 bf1 = *(const f16x8*)(w1b + k0);
        acc0 = __builtin_amdgcn_mfma_f32_16x16x32_f16(af, bf0, acc0, 0, 0, 0);
        acc1 = __builtin_amdgcn_mfma_f32_16x16x32_f16(af, bf1, acc1, 0, 0, 0);
    }
    {
        f16x8 af;
        #pragma unroll
        for (int e = 0; e < 8; ++e) {
            int k = 480 + kg * 8 + e;
            af[e] = (k < F_IN) ? (h16)xr[k] : (h16)0.f;
        }
        f16x8 bf0 = *(const f16x8*)(w1a + 480);
        f16x8 bf1 = *(const f16x8*)(w1b + 480);
        acc0 = __builtin_amdgcn_mfma_f32_16x16x32_f16(af, bf0, acc0, 0, 0, 0);
        acc1 = __builtin_amdgcn_mfma_f32_16x16x32_f16(af, bf1, acc1, 0, 0, 0);
    }

    float g0 = gamma[c0], g1 = gamma[c0 + 16];
    float be0 = beta[c0], be1 = beta[c0 + 16];
    h16* hb = hbuf[w];
    #pragma unroll
    for (int i = 0; i < 4; ++i) {
        float a0 = acc0[i], a1 = acc1[i];
        float s = a0 + a1;
        s += __shfl_xor(s, 1); s += __shfl_xor(s, 2);
        s += __shfl_xor(s, 4); s += __shfl_xor(s, 8);
        float mu = s * (1.0f / 32.0f);
        float d0 = a0 - mu, d1 = a1 - mu;
        float vv = d0 * d0 + d1 * d1;
        vv += __shfl_xor(vv, 1); vv += __shfl_xor(vv, 2);
        vv += __shfl_xor(vv, 4); vv += __shfl_xor(vv, 8);
        float is = rsqrtf(vv * (1.0f / 32.0f) + LN_EPS);
        float h0v = fmaxf(fmaf(d0 * is, g0, be0), 0.f);
        float h1v = fmaxf(fmaf(d1 * is, g1, be1), 0.f);
        int r = kg * 4 + i;
        hb[r * 32 + ((((c0 >> 3) ^ i) & 3) << 3) + (c0 & 7)] = (h16)h0v;
        hb[r * 32 + ((((2 + (c0 >> 3)) ^ i) & 3) << 3) + (c0 & 7)] = (h16)h1v;
    }
    asm volatile("s_waitcnt lgkmcnt(0)" ::: "memory");
    __builtin_amdgcn_sched_barrier(0);

    f16x8 ah = *(const f16x8*)(hb + c0 * 32 + (((kg ^ (c0 & 3)) & 3) << 3));

    f32x4 oc[4];
    #pragma unroll
    for (int tl = 0; tl < 4; ++tl) {
        float bb = b2[tl * 16 + c0];
        f32x4 ci = {bb, bb, bb, bb};
        f16x8 bw = *(const f16x8*)(w2t + (tl * 16 + c0) * 32 + kg * 8);
        oc[tl] = __builtin_amdgcn_mfma_f32_16x16x32_f16(ah, bw, ci, 0, 0, 0);
    }

    #pragma unroll
    for (int i = 0; i < 4; ++i) {
        float ss = oc[0][i] * oc[0][i] + oc[1][i] * oc[1][i]
                 + oc[2][i] * oc[2][i] + oc[3][i] * oc[3][i];
        ss += __shfl_xor(ss, 1); ss += __shfl_xor(ss, 2);
        ss += __shfl_xor(ss, 4); ss += __shfl_xor(ss, 8);
        float sc = 1.0f / fmaxf(sqrtf(ss), 1e-12f);
        int row = gr0 + kg * 4 + i;
        if (row < N) {
            #pragma unroll
            for (int tl = 0; tl < 4; ++tl)
                h0[(size_t)row * DD + tl * 16 + c0] = oc[tl][i] * sc;
        }
    }
}

// ---------------------------------------------------------------------------
__global__ void zero_k(int* __restrict__ p, int n)
{
    int i = blockIdx.x * blockDim.x + threadIdx.x;
    int stride = gridDim.x * blockDim.x;
    for (; i < n; i += stride) p[i] = 0;
}

// ---------------------------------------------------------------------------
// binq v2 (round-7, measured good): wave-autonomous two-pass span binner.
// ---------------------------------------------------------------------------
__global__ __launch_bounds__(256)
void binq_k(const int* __restrict__ erow, const int* __restrict__ ecol, int M,
            unsigned* __restrict__ queue, int* __restrict__ qcnt,
            int cw, unsigned magic)
{
    const int wid  = blockIdx.x * 4 + (threadIdx.x >> 6);
    const int lane = threadIdx.x & 63;
    const int nw   = gridDim.x * 4;
    const int cls  = blockIdx.x & 7;

    for (int s0 = wid * SPAN; s0 < M; s0 += nw * SPAN) {
        const int e1 = min(s0 + SPAN, M);
        int tc[8] = {0, 0, 0, 0, 0, 0, 0, 0};
        for (int i = s0 + lane; i < e1; i += 64) {
            int c = ecol[i];
            unsigned p = (unsigned)(((unsigned long long)(unsigned)c * magic) >> 32);
            #pragma unroll
            for (int pp = 0; pp < 8; ++pp) tc[pp] += (p == (unsigned)pp) ? 1 : 0;
        }
        #pragma unroll
        for (int pp = 0; pp < 8; ++pp) {
            #pragma unroll
            for (int m = 1; m < 64; m <<= 1) tc[pp] += __shfl_xor(tc[pp], m);
        }
        int val = tc[0];
        #pragma unroll
        for (int pp = 1; pp < 8; ++pp) val = (lane == pp) ? tc[pp] : val;
        int base = 0;
        if (lane < 8) base = atomicAdd(&qcnt[lane * 8 + cls], val);
        int bases[8], run[8];
        #pragma unroll
        for (int pp = 0; pp < 8; ++pp) { bases[pp] = __shfl(base, pp); run[pp] = 0; }

        for (int i0 = s0; i0 < e1; i0 += 64) {
            int i = i0 + lane;
            bool act = i < e1;
            int c = act ? ecol[i] : 0;
            int r = act ? erow[i] : 0;
            unsigned p = act ? (unsigned)(((unsigned long long)(unsigned)c * magic) >> 32)
                             : 0xFFu;
            unsigned pk = (unsigned)r | ((unsigned)(c - (int)p * cw) << 17);
            #pragma unroll
            for (int pp = 0; pp < 8; ++pp) {
                unsigned long long mm = __ballot(p == (unsigned)pp);
                if (p == (unsigned)pp) {
                    int rank = __popcll(mm & ((1ull << lane) - 1ull));
                    queue[(size_t)(pp * 8 + cls) * QCAP + bases[pp] + run[pp] + rank] = pk;
                }
                run[pp] += (int)__popcll(mm);
            }
        }
    }
}

// ---------------------------------------------------------------------------
// countq v3: ONE block per cohort, 50KB LDS histogram (12500 bins), 4-way
// unrolled L2-hot queue scan, plain coalesced cnt stores. Zero global atomics.
// ---------------------------------------------------------------------------
__global__ __launch_bounds__(1024)
void countq_k(const unsigned* __restrict__ queue, const int* __restrict__ qcnt,
              int* __restrict__ cnt, int cw)
{
    __shared__ int lc[12500];
    const int p = blockIdx.x;
    const int tid = threadIdx.x;

    for (int i = tid; i < cw; i += 1024) lc[i] = 0;
    __syncthreads();

    #pragma unroll 1
    for (int sq = 0; sq < 8; ++sq) {
        const int n = qcnt[p * 8 + sq];
        const unsigned* q = queue + (size_t)(p * 8 + sq) * QCAP;
        int i = tid;
        for (; i + 3 * 1024 < n; i += 4 * 1024) {
            unsigned e0 = q[i];
            unsigned e1 = q[i + 1024];
            unsigned e2 = q[i + 2048];
            unsigned e3 = q[i + 3072];
            atomicAdd(&lc[e0 >> 17], 1);
            atomicAdd(&lc[e1 >> 17], 1);
            atomicAdd(&lc[e2 >> 17], 1);
            atomicAdd(&lc[e3 >> 17], 1);
        }
        for (; i < n; i += 1024)
            atomicAdd(&lc[q[i] >> 17], 1);
    }
    __syncthreads();

    int* cb = cnt + p * cw;
    for (int i = tid; i < cw; i += 1024) cb[i] = lc[i];
}

// ---------------------------------------------------------------------------
// Deterministic monotone scan: A) per-block reduce, B) scan block sums,
// C) per-block scan + dinv. start[] is globally ascending by node index.
// ---------------------------------------------------------------------------
__global__ __launch_bounds__(256)
void scanA_k(const int* __restrict__ cnt, int* __restrict__ bsum, int N)
{
    __shared__ int sd[256];
    int t = threadIdx.x;
    int v = blockIdx.x * 256 + t;
    sd[t] = (v < N) ? cnt[v] : 0;
    __syncthreads();
    #pragma unroll
    for (int o = 128; o > 0; o >>= 1) {
        if (t < o) sd[t] += sd[t + o];
        __syncthreads();
    }
    if (t == 0) bsum[blockIdx.x] = sd[0];
}

__global__ __launch_bounds__(512)
void scanB_k(const int* __restrict__ bsum, int* __restrict__ bbase, int NB)
{
    __shared__ int sd[512];
    int t = threadIdx.x;
    int v = (t < NB) ? bsum[t] : 0;
    sd[t] = v;
    __syncthreads();
    #pragma unroll
    for (int o = 1; o < 512; o <<= 1) {
        int tmp = (t >= o) ? sd[t - o] : 0;
        __syncthreads();
        sd[t] += tmp;
        __syncthreads();
    }
    if (t < NB) bbase[t] = sd[t] - v;   // exclusive base
}

__global__ __launch_bounds__(256)
void scanC_k(const int* __restrict__ cnt, const int* __restrict__ bbase,
             int* __restrict__ start, float* __restrict__ dinv, int N)
{
    __shared__ int sd[256];
    int t = threadIdx.x;
    int v = blockIdx.x * 256 + t;
    int c = (v < N) ? cnt[v] : 0;
    sd[t] = c;
    __syncthreads();
    #pragma unroll
    for (int o = 1; o < 256; o <<= 1) {
        int tmp = (t >= o) ? sd[t - o] : 0;
        __syncthreads();
        sd[t] += tmp;
        __syncthreads();
    }
    if (v < N) {
        start[v] = bbase[blockIdx.x] + sd[t] - c;
        dinv[v]  = (c > 0) ? rsqrtf((float)c) : 0.0f;
    }
}

// ---------------------------------------------------------------------------
// fillq v4 (round-10, measured good): LDS counting sort per window,
// 1024 threads, 4-way unrolled scan.
// ---------------------------------------------------------------------------
__global__ __launch_bounds__(1024)
void fillq_k(const unsigned* __restrict__ queue, const int* __restrict__ qcnt,
             const int* __restrict__ start, int* __restrict__ cursor,
             int* __restrict__ csr_src, int cw, int M, int N)
{
    __shared__ int loff[FWN + 1];
    __shared__ int lcur[FWN];
    __shared__ unsigned lbuf[FCAP];

    const int tid = threadIdx.x;
    const int p  = blockIdx.x & 7;
    const int w  = blockIdx.x >> 3;
    const int c0 = w * FWN;
    const int wn = min(FWN, cw - c0);
    const int gn0 = p * cw + c0;

    for (int i = tid; i <= wn; i += 1024) {
        int g = gn0 + i;
        loff[i] = (g < N) ? start[g] : M;
    }
    for (int i = tid; i < wn; i += 1024) lcur[i] = 0;
    __syncthreads();

    const int base = loff[0];
    const int span = loff[wn] - base;

    if (span <= FCAP) {
        #pragma unroll 1
        for (int sq = 0; sq < 8; ++sq) {
            const int n = qcnt[p * 8 + sq];
            const unsigned* q = queue + (size_t)(p * 8 + sq) * QCAP;
            int i = tid;
            for (; i + 3 * 1024 < n; i += 4 * 1024) {
                unsigned e0 = q[i];
                unsigned e1 = q[i + 1024];
                unsigned e2 = q[i + 2048];
                unsigned e3 = q[i + 3072];
                int cl0 = (int)(e0 >> 17) - c0;
                int cl1 = (int)(e1 >> 17) - c0;
                int cl2 = (int)(e2 >> 17) - c0;
                int cl3 = (int)(e3 >> 17) - c0;
                if ((unsigned)cl0 < (unsigned)wn)
                    lbuf[loff[cl0] - base + atomicAdd(&lcur[cl0], 1)] = e0 & 0x1FFFFu;
                if ((unsigned)cl1 < (unsigned)wn)
                    lbuf[loff[cl1] - base + atomicAdd(&lcur[cl1], 1)] = e1 & 0x1FFFFu;
                if ((unsigned)cl2 < (unsigned)wn)
                    lbuf[loff[cl2] - base + atomicAdd(&lcur[cl2], 1)] = e2 & 0x1FFFFu;
                if ((unsigned)cl3 < (unsigned)wn)
                    lbuf[loff[cl3] - base + atomicAdd(&lcur[cl3], 1)] = e3 & 0x1FFFFu;
            }
            for (; i < n; i += 1024) {
                unsigned pk = q[i];
                int cl = (int)(pk >> 17) - c0;
                if ((unsigned)cl < (unsigned)wn)
                    lbuf[loff[cl] - base + atomicAdd(&lcur[cl], 1)] = pk & 0x1FFFFu;
            }
        }
        __syncthreads();
        for (int i = tid; i < span; i += 1024)
            csr_src[base + i] = (int)lbuf[i];
    } else {
        #pragma unroll 1
        for (int sq = 0; sq < 8; ++sq) {
            int n = qcnt[p * 8 + sq];
            const unsigned* q = queue + (size_t)(p * 8 + sq) * QCAP;
            for (int i = tid; i < n; i += 1024) {
                unsigned pk = q[i];
                int cl = (int)(pk >> 17) - c0;
                if ((unsigned)cl < (unsigned)wn) {
                    int c = gn0 + cl;
                    int pos = start[c] + atomicAdd(&cursor[c], 1);
                    csr_src[pos] = (int)(pk & 0x1FFFFu);
                }
            }
        }
    }
}

// ---------------------------------------------------------------------------
// mirror[v][d-pair] = dinv[v] * h[v][2d..2d+1] as packed 2xf16
// ---------------------------------------------------------------------------
__global__ __launch_bounds__(256)
void mkmir_k(const float* __restrict__ h, const float* __restrict__ dinv,
             unsigned* __restrict__ m, int N)
{
    int i = blockIdx.x * 256 + threadIdx.x;
    if (i >= N * 32) return;
    float2 v = ((const float2*)h)[i];
    float dv = dinv[i >> 5];
    f16x2 hv;
    hv[0] = (h16)(v.x * dv);
    hv[1] = (h16)(v.y * dv);
    m[i] = __builtin_bit_cast(unsigned, hv);
}

// ---------------------------------------------------------------------------
// Propagation: 2 nodes per wave (32 lanes each, lane = u32 d-pair),
// 8 independent gathers in flight per lane.
// hout[v] = dinv[v] * sum_r mirror[r]
// ---------------------------------------------------------------------------
__global__ __launch_bounds__(256)
void prop16_k(const unsigned* __restrict__ min_, float* __restrict__ hout,
              unsigned* __restrict__ mout,
              const int* __restrict__ start, const int* __restrict__ cnt,
              const int* __restrict__ csr_src, const float* __restrict__ dinv, int N)
{
    int v = blockIdx.x * 8 + (threadIdx.x >> 5);
    int l = threadIdx.x & 31;
    if (v >= N) return;
    int s = start[v];
    int e = s + cnt[v];
    float dv = dinv[v];
    float a0 = 0.0f, a1 = 0.0f;
    int i = s;
    for (; i + 7 < e; i += 8) {
        unsigned u0 = min_[(size_t)csr_src[i + 0] * 32 + l];
        unsigned u1 = min_[(size_t)csr_src[i + 1] * 32 + l];
        unsigned u2 = min_[(size_t)csr_src[i + 2] * 32 + l];
        unsigned u3 = min_[(size_t)csr_src[i + 3] * 32 + l];
        unsigned u4 = min_[(size_t)csr_src[i + 4] * 32 + l];
        unsigned u5 = min_[(size_t)csr_src[i + 5] * 32 + l];
        unsigned u6 = min_[(size_t)csr_src[i + 6] * 32 + l];
        unsigned u7 = min_[(size_t)csr_src[i + 7] * 32 + l];
        f16x2 h0v = __builtin_bit_cast(f16x2, u0);
        f16x2 h1v = __builtin_bit_cast(f16x2, u1);
        f16x2 h2v = __builtin_bit_cast(f16x2, u2);
        f16x2 h3v = __builtin_bit_cast(f16x2, u3);
        f16x2 h4v = __builtin_bit_cast(f16x2, u4);
        f16x2 h5v = __builtin_bit_cast(f16x2, u5);
        f16x2 h6v = __builtin_bit_cast(f16x2, u6);
        f16x2 h7v = __builtin_bit_cast(f16x2, u7);
        a0 += ((float)h0v[0] + (float)h1v[0]) + ((float)h2v[0] + (float)h3v[0])
            + ((float)h4v[0] + (float)h5v[0]) + ((float)h6v[0] + (float)h7v[0]);
        a1 += ((float)h0v[1] + (float)h1v[1]) + ((float)h2v[1] + (float)h3v[1])
            + ((float)h4v[1] + (float)h5v[1]) + ((float)h6v[1] + (float)h7v[1]);
    }
    for (; i < e; ++i) {
        int r = csr_src[i];
        f16x2 hv = __builtin_bit_cast(f16x2, min_[(size_t)r * 32 + l]);
        a0 += (float)hv[0];
        a1 += (float)hv[1];
    }
    float r0 = dv * a0, r1 = dv * a1;
    float2 st; st.x = r0; st.y = r1;
    *(float2*)(hout + (size_t)v * DD + 2 * l) = st;
    if (mout) {
        f16x2 mv;
        mv[0] = (h16)(dv * r0);
        mv[1] = (h16)(dv * r1);
        mout[(size_t)v * 32 + l] = __builtin_bit_cast(unsigned, mv);
    }
}

// ---------------------------------------------------------------------------
extern "C" void kernel_launch(void* const* d_in, const int* in_sizes, int n_in,
                              void* d_out, int out_size, void* d_ws, size_t ws_size,
                              hipStream_t stream)
{
    const float* x     = (const float*)d_in[0];
    const int*   ei    = (const int*)  d_in[1];
    const float* W1    = (const float*)d_in[2];
    const float* b1    = (const float*)d_in[3];
    const float* gamma = (const float*)d_in[4];
    const float* beta  = (const float*)d_in[5];
    const float* W2    = (const float*)d_in[6];
    const float* b2    = (const float*)d_in[7];
    float* out = (float*)d_out;

    const int N = in_sizes[0] / F_IN;       // 100000
    const int M = in_sizes[1] / 2;          // 3300000
    const int cw = (N + 7) / 8;             // 12500
    const unsigned magic = (unsigned)((0x100000000ULL + cw - 1) / cw);
    const int NB = (N + 255) / 256;         // 391 scan blocks
    const int* erow = ei;
    const int* ecol = ei + M;

    // workspace layout (ints)
    int* wsI = (int*)d_ws;
    int*   cnt     = wsI;                               // N
    int*   cursor  = wsI + N;                           // N
    int*   qcnt    = wsI + 2 * N + 4;                   // 64
    int*   bsum    = wsI + 2 * N + 68;                  // 512
    int*   bbase   = wsI + 2 * N + 580;                 // 512
    int*   startv  = wsI + 2 * N + 1092;                // N
    float* dinv    = (float*)(wsI + 3 * N + 1092);      // N
    h16*   w1t     = (h16*)(wsI + 4 * N + 1092);        // 8192 ints
    h16*   w2t     = (h16*)(wsI + 4 * N + 1092 + 8192); // 1024 ints
    int*   csr_src = wsI + 4 * N + 1092 + 9216;         // M
    unsigned* queue = (unsigned*)(csr_src + M);         // 64*QCAP
    unsigned* mir0 = queue;                             // overlays queue
    unsigned* mir1 = mir0 + (size_t)N * 32;

    // zero cursor + qcnt (cnt is fully overwritten by countq v3)
    zero_k<<<512, 256, 0, stream>>>(wsI + N, N + 68);
    prep_k<<<(32 * 512 + 64 * 32 + 255) / 256, 256, 0, stream>>>(W1, W2, w1t, w2t);

    encoder_k<<<(N + 63) / 64, 256, 0, stream>>>(x, w1t, b1, gamma, beta, w2t, b2, out, N);

    binq_k<<<256, 256, 0, stream>>>(erow, ecol, M, queue, qcnt, cw, magic);

    countq_k<<<8, 1024, 0, stream>>>(queue, qcnt, cnt, cw);

    scanA_k<<<NB, 256, 0, stream>>>(cnt, bsum, N);
    scanB_k<<<1, 512, 0, stream>>>(bsum, bbase, NB);
    scanC_k<<<NB, 256, 0, stream>>>(cnt, bbase, startv, dinv, N);

    const int NWF = (cw + FWN - 1) / FWN;   // 28
    fillq_k<<<NWF * 8, 1024, 0, stream>>>(queue, qcnt, startv, cursor, csr_src, cw, M, N);

    float* h0 = out;
    float* h1 = out + (size_t)N * DD;
    float* h2 = out + 2 * (size_t)N * DD;

    mkmir_k<<<(N * 32 + 255) / 256, 256, 0, stream>>>(h0, dinv, mir0, N);
    prop16_k<<<(N + 7) / 8, 256, 0, stream>>>(mir0, h1, mir1, startv, cnt, csr_src, dinv, N);
    prop16_k<<<(N + 7) / 8, 256, 0, stream>>>(mir1, h2, (unsigned*)nullptr, startv, cnt, csr_src, dinv, N);
}